// Round 1
// baseline (79.843 us; speedup 1.0000x reference)
//
#include <hip/hip_runtime.h>
#include <math.h>

#define TPB 256
#define WPB (TPB / 64)

// Fused single-kernel multi-label ranking loss.
// One 64-lane wave per sample (D=256 fast path): lane l loads scores[b][4l..4l+3]
// as one float4 (1 KiB per wave -> ideal coalescing). idx + positive scores are
// wave-uniform (readfirstlane-scalarized b) -> s_load broadcasts.
// Block partial -> double atomicAdd into ws accumulators; ticket counter picks
// the last block to do the division and write out[0]. Counter/accs zeroed by a
// 32-B hipMemsetAsync node (graph-capturable).
__global__ __launch_bounds__(TPB) void mlrl_fused(
        const float* __restrict__ scores,
        const int*   __restrict__ idx,
        const int*   __restrict__ ndev,
        int total_scores, int total_idx,
        double* __restrict__ accs,        // [0]=loss, [1]=pairs
        unsigned int* __restrict__ counter,
        int nblk,
        float* __restrict__ out) {

    const int D    = *ndev;
    const int lane = threadIdx.x & 63;
    // wave index, forced uniform so all per-sample addresses scalarize
    const int wv = __builtin_amdgcn_readfirstlane((int)threadIdx.x) >> 6;
    const int gw      = blockIdx.x * WPB + wv;   // global wave id
    const int gstride = gridDim.x * WPB;

    float loss = 0.0f, pairs = 0.0f;

    const bool fast = (D == 256) &&
                      ((long long)total_idx * 32LL == (long long)total_scores) &&
                      ((total_scores & 255) == 0);

    if (fast) {
        const int B = total_scores >> 8;          // bench: 2048
        for (int b = gw; b < B; b += gstride) {
            const int rb = b << 8;
            const int ib = b << 3;

            // uniform idx loads (SGPR, s_load_dwordx4 x2)
            const int4 i0 = *reinterpret_cast<const int4*>(idx + ib);
            const int4 i1 = *reinterpret_cast<const int4*>(idx + ib + 4);
            int ik[8] = { i0.x, i0.y, i0.z, i0.w, i1.x, i1.y, i1.z, i1.w };

            // per-lane row chunk: 4 contiguous floats
            const float4 v = *reinterpret_cast<const float4*>(scores + rb + (lane << 2));

            // positive scores (uniform s_loads); dedup -> valid mask
            float c[8];                // c[k] = 1 - s_pos[k], or -inf if dup
            int P = 0;
            #pragma unroll
            for (int k = 0; k < 8; ++k) {
                bool dup = false;
                #pragma unroll
                for (int j = 0; j < 8; ++j)
                    if (j < k) dup |= (ik[j] == ik[k]);
                const float pscore = scores[rb + ik[k]];
                if (!dup) { ++P; c[k] = 1.0f - pscore; }
                else      { c[k] = -INFINITY; }
            }

            const int e0 = lane << 2;
            const float se[4] = { v.x, v.y, v.z, v.w };
            #pragma unroll
            for (int j = 0; j < 4; ++j) {
                const int e = e0 + j;
                bool pos = false;
                #pragma unroll
                for (int k = 0; k < 8; ++k) pos |= (ik[k] == e);
                const float s = pos ? -INFINITY : se[j];   // -inf kills all terms
                #pragma unroll
                for (int k = 0; k < 8; ++k)
                    loss += fmaxf(0.0f, s + c[k]);         // relu(s_n - s_p + 1)
            }
            if (lane == 0) pairs += (float)((256 - P) * P);
        }
    } else if (D > 0) {
        // Generic runtime-D/K fallback (not hit by the bench shape).
        const int B = total_scores / D;
        const int K = (B > 0) ? (total_idx / B) : 0;
        for (int b = gw; b < B; b += gstride) {
            const int rb = b * D, ib = b * K;
            int P = 0;
            for (int k = 0; k < K; ++k) {
                bool dup = false;
                for (int j = 0; j < k; ++j) dup |= (idx[ib + j] == idx[ib + k]);
                if (!dup) ++P;
            }
            for (int d = lane; d < D; d += 64) {
                const float s = scores[rb + d] + 1.0f;
                bool pos = false;
                for (int k = 0; k < K; ++k) pos |= (idx[ib + k] == d);
                if (!pos) {
                    for (int k = 0; k < K; ++k) {
                        bool dup = false;
                        for (int j = 0; j < k; ++j) dup |= (idx[ib + j] == idx[ib + k]);
                        if (!dup) {
                            const float t = s - scores[rb + idx[ib + k]];
                            loss += (t > 0.0f) ? t : 0.0f;
                        }
                    }
                }
            }
            if (lane == 0) pairs += (float)((D - P) * P);
        }
    }

    // ---- block reduction ----
    #pragma unroll
    for (int off = 32; off > 0; off >>= 1)
        loss += __shfl_down(loss, off, 64);
    // pairs only ever lives on lane 0 of each wave -> no shuffle needed

    __shared__ float2 red[WPB];
    if (lane == 0) red[wv] = make_float2(loss, pairs);
    __syncthreads();

    if (threadIdx.x == 0) {
        float L = red[0].x, Pp = red[0].y;
        #pragma unroll
        for (int w = 1; w < WPB; ++w) { L += red[w].x; Pp += red[w].y; }

        atomicAdd(&accs[0], (double)L);
        atomicAdd(&accs[1], (double)Pp);
        __threadfence();
        const unsigned prev = atomicAdd(counter, 1u);
        if (prev == (unsigned)nblk - 1u) {
            // last block: totals are complete (release via fence+atomic above)
            __threadfence();
            const double l = atomicAdd(&accs[0], 0.0);   // atomic read
            const double p = atomicAdd(&accs[1], 0.0);
            out[0] = (p > 0.0) ? (float)(l / (p < 1.0 ? 1.0 : p)) : 0.0f;
        }
    }
}

extern "C" void kernel_launch(void* const* d_in, const int* in_sizes, int n_in,
                              void* d_out, int out_size, void* d_ws, size_t ws_size,
                              hipStream_t stream) {
    const float* scores = (const float*)d_in[0];
    const int*   idx    = (const int*)d_in[1];
    const int*   ndev   = (const int*)d_in[2];

    const int total_scores = in_sizes[0];  // B*D
    const int total_idx    = in_sizes[1];  // B*K

    double*       accs    = (double*)d_ws;
    unsigned int* counter = (unsigned int*)((char*)d_ws + 16);

    // zero accumulators + ticket counter (tiny, graph-capturable)
    hipMemsetAsync(d_ws, 0, 32, stream);

    // 4 waves/block, 1 sample/wave at D=256 -> 1024 score elems per block
    int nblk = total_scores >> 10;
    if (nblk < 1)    nblk = 1;
    if (nblk > 2048) nblk = 2048;

    mlrl_fused<<<nblk, TPB, 0, stream>>>(scores, idx, ndev,
                                         total_scores, total_idx,
                                         accs, counter, nblk, (float*)d_out);
}